// Round 1
// baseline (107.368 us; speedup 1.0000x reference)
//
#include <hip/hip_runtime.h>

constexpr int Dd = 128, Hh = 128, Ww = 128;
constexpr int NVOX = Dd * Hh * Ww;      // 2^21 per batch
constexpr int NB = 2;
constexpr int NC = 4;
constexpr int TOTAL = NB * NVOX;        // 4,194,304 voxels
constexpr int NWORDS = TOTAL / 64;      // 65536 mask words

struct alignas(16) MaskW { unsigned long long m1, m03; };

__device__ __forceinline__ unsigned short f2bf(float f) {
    unsigned int u = __float_as_uint(f);
    return (unsigned short)((u + 0x7FFFu + ((u >> 16) & 1u)) >> 16);  // RNE
}
__device__ __forceinline__ float bf2f_lo(unsigned int u) { return __uint_as_float(u << 16); }
__device__ __forceinline__ float bf2f_hi(unsigned int u) { return __uint_as_float(u & 0xFFFF0000u); }

// Kernel 1: 4 voxels/thread via float4/int4 loads. Argmax + CE via base-2
// logsumexp (exp2f/log2f lower to single v_exp_f32/v_log_f32 — HW-native
// base, ~half the VALU of __ocml expf/logf). Packs predicate nibbles,
// assembles 64-voxel mask words through LDS. Also zeroes d_out (safe:
// kernel2 is stream-ordered after).
__global__ __launch_bounds__(256) void argmax_ce_kernel(
    const float4* __restrict__ x4, const int4* __restrict__ y4,
    MaskW* __restrict__ Mw, unsigned short* __restrict__ ce,
    float* __restrict__ out)
{
    constexpr float L2E = 1.44269504088896f;   // log2(e)
    constexpr float LN2 = 0.69314718055995f;   // ln(2)
    int tid = threadIdx.x;
    if (blockIdx.x == 0 && tid == 0) out[0] = 0.f;

    int gv = blockIdx.x * 256 + tid;          // float4-group index (4 voxels)
    int b  = gv >> 19;                         // NVOX/4 = 2^19
    int vv = gv & ((NVOX / 4) - 1);
    const float4* xb = x4 + (size_t)b * (NC * NVOX / 4) + vv;
    float4 a0 = xb[0];
    float4 a1 = xb[NVOX / 4];
    float4 a2 = xb[2 * (NVOX / 4)];
    float4 a3 = xb[3 * (NVOX / 4)];
    int4 yi = y4[gv];

    float X0[4] = {a0.x, a0.y, a0.z, a0.w};
    float X1[4] = {a1.x, a1.y, a1.z, a1.w};
    float X2[4] = {a2.x, a2.y, a2.z, a2.w};
    float X3[4] = {a3.x, a3.y, a3.z, a3.w};
    int   Y[4]  = {yi.x, yi.y, yi.z, yi.w};

    unsigned int nib1 = 0, nib03 = 0;
    unsigned short cv[4];
    #pragma unroll
    for (int c = 0; c < 4; ++c) {
        float x0 = X0[c], x1 = X1[c], x2 = X2[c], x3 = X3[c];
        int p = 0; float m = x0;
        if (x1 > m) { m = x1; p = 1; }
        if (x2 > m) { m = x2; p = 2; }
        if (x3 > m) { m = x3; p = 3; }
        // base-2 logsumexp: ce = ln2*log2( sum 2^((xi-m)*log2e) ) + m - x[y]
        float s = exp2f((x0 - m) * L2E) + exp2f((x1 - m) * L2E)
                + exp2f((x2 - m) * L2E) + exp2f((x3 - m) * L2E);
        int yy = Y[c];
        float xy = (yy == 0) ? x0 : ((yy == 1) ? x1 : ((yy == 2) ? x2 : x3));
        cv[c] = f2bf(fmaf(log2f(s), LN2, m - xy));
        nib1  |= (unsigned)(p == 1) << c;
        nib03 |= (unsigned)(p == 0 || p == 3) << c;
    }
    ushort4 cev = {cv[0], cv[1], cv[2], cv[3]};
    ((ushort4*)ce)[gv] = cev;                  // 8B/lane coalesced store

    // assemble mask words: block covers 1024 voxels = 16 words;
    // word w <- threads [16w,16w+16), nibble k at bit 4k.
    __shared__ unsigned int nibs[256];
    nibs[tid] = nib1 | (nib03 << 8);
    __syncthreads();
    if (tid < 16) {
        int base = tid * 16;
        unsigned long long m1 = 0, m03 = 0;
        #pragma unroll
        for (int k = 0; k < 16; ++k) {
            unsigned int nv = nibs[base + k];
            m1  |= (unsigned long long)(nv & 0xFu) << (4 * k);
            m03 |= (unsigned long long)((nv >> 8) & 0xFu) << (4 * k);
        }
        MaskW mw; mw.m1 = m1; mw.m03 = m03;
        Mw[blockIdx.x * 16 + tid] = mw;
    }
}

// Kernel 2: one block per (b,d) plane. ALL global loads (3 MaskW planes +
// 8 uint4 of ce) are issued up front so the ce HBM latency overlaps the
// mask staging wait + dilation VALU (this kernel runs at 1 wave/SIMD —
// no TLP to hide latency, so ILP must do it). Word-level 3x3x3 dilation
// of the predicate bitmasks -> critical mask; reduce bf16 ce over set
// bits from the prefetched registers. One atomicAdd per block.
__global__ __launch_bounds__(256) void crit_sum_kernel(
    const MaskW* __restrict__ Mw, const unsigned short* __restrict__ ce,
    float* __restrict__ out)
{
    __shared__ unsigned long long sm1[3][256];
    __shared__ unsigned long long sm03[3][256];
    __shared__ unsigned long long critw[256];
    __shared__ float wsum[4];

    int tid = threadIdx.x;
    int bid = blockIdx.x;          // b*128 + d
    int d = bid & 127;

    // ---- issue mask-plane loads (3x 16B/lane) ----
    unsigned long long pm1[3], pm03[3];
    #pragma unroll
    for (int pl = 0; pl < 3; ++pl) {
        int dp = d - 1 + pl;
        unsigned long long a = 0, c = 0;
        if ((unsigned)dp < 128u) {
            MaskW m = Mw[(bid - d + dp) * 256 + tid];
            a = m.m1; c = m.m03;
        }
        pm1[pl] = a; pm03[pl] = c;
    }

    // ---- issue ce prefetch (8x 16B/lane = 32 VGPR) before any barrier ----
    const uint4* cep = (const uint4*)(ce + ((size_t)bid << 14));
    uint4 u[8];
    #pragma unroll
    for (int j = 0; j < 8; ++j) u[j] = cep[j * 256 + tid];

    // ---- stage masks to LDS (waits only on the 3 MaskW loads) ----
    #pragma unroll
    for (int pl = 0; pl < 3; ++pl) {
        sm1[pl][tid]  = pm1[pl];
        sm03[pl][tid] = pm03[pl];
    }
    __syncthreads();

    int h = tid >> 1, k = tid & 1;
    unsigned long long E1 = 0, E03 = 0;
    #pragma unroll
    for (int pl = 0; pl < 3; ++pl) {
        #pragma unroll
        for (int dy = -1; dy <= 1; ++dy) {
            int hh = h + dy;
            if ((unsigned)hh < 128u) {
                int idx = hh * 2 + k;
                int adj = hh * 2 + (k ^ 1);
                unsigned long long m1 = sm1[pl][idx],  a1 = sm1[pl][adj];
                unsigned long long m3 = sm03[pl][idx], a3 = sm03[pl][adj];
                unsigned long long s1 = m1 | (m1 << 1) | (m1 >> 1);
                unsigned long long s3 = m3 | (m3 << 1) | (m3 >> 1);
                if (k == 0) { s1 |= (a1 & 1ull) << 63; s3 |= (a3 & 1ull) << 63; }
                else        { s1 |= (a1 >> 63);        s3 |= (a3 >> 63); }
                E1  |= s1;
                E03 |= s3;
            }
        }
    }
    unsigned long long C1 = sm1[1][tid], C03 = sm03[1][tid];
    critw[tid] = (C1 & E03) | (C03 & E1);
    __syncthreads();

    // ---- reduce prefetched bf16 ce over this plane's set bits ----
    float s = 0.f;
    #pragma unroll
    for (int j = 0; j < 8; ++j) {
        int idx = j * 256 + tid;               // [0, 2048)
        uint4 uu = u[j];
        unsigned long long w = critw[idx >> 3];
        int bb = (idx & 7) * 8;
        if ((w >> bb)       & 1ull) s += bf2f_lo(uu.x);
        if ((w >> (bb + 1)) & 1ull) s += bf2f_hi(uu.x);
        if ((w >> (bb + 2)) & 1ull) s += bf2f_lo(uu.y);
        if ((w >> (bb + 3)) & 1ull) s += bf2f_hi(uu.y);
        if ((w >> (bb + 4)) & 1ull) s += bf2f_lo(uu.z);
        if ((w >> (bb + 5)) & 1ull) s += bf2f_hi(uu.z);
        if ((w >> (bb + 6)) & 1ull) s += bf2f_lo(uu.w);
        if ((w >> (bb + 7)) & 1ull) s += bf2f_hi(uu.w);
    }
    #pragma unroll
    for (int off = 32; off; off >>= 1) s += __shfl_down(s, off, 64);
    if ((tid & 63) == 0) wsum[tid >> 6] = s;
    __syncthreads();
    if (tid == 0) {
        float t = wsum[0] + wsum[1] + wsum[2] + wsum[3];
        atomicAdd(out, t * 0.5f);   // mean over NB=2 batches
    }
}

extern "C" void kernel_launch(void* const* d_in, const int* in_sizes, int n_in,
                              void* d_out, int out_size, void* d_ws, size_t ws_size,
                              hipStream_t stream) {
    const float4* x4 = (const float4*)d_in[0];
    const int4*   y4 = (const int4*)d_in[1];
    MaskW* Mw = (MaskW*)d_ws;                                        // 1 MB
    unsigned short* ce = (unsigned short*)((char*)d_ws + (size_t)NWORDS * 16);  // 8.4 MB bf16
    float* out = (float*)d_out;

    argmax_ce_kernel<<<TOTAL / 1024, 256, 0, stream>>>(x4, y4, Mw, ce, out);
    crit_sum_kernel<<<NB * Dd, 256, 0, stream>>>(Mw, ce, out);
}